// Round 8
// baseline (3520.105 us; speedup 1.0000x reference)
//
#include <hip/hip_runtime.h>
#include <math.h>

#define HID 128
#define PAD 138

typedef __attribute__((ext_vector_type(8))) short bf16x8;
typedef __attribute__((ext_vector_type(16))) float f32x16;
typedef unsigned short us;

__device__ __forceinline__ float silu_f(float v) {
    return v / (1.0f + __expf(-v));
}
__device__ __forceinline__ float sigmoid_f(float v) {
    return 1.0f / (1.0f + __expf(-v));
}
__device__ __forceinline__ us bf16trunc(float f) {
    return (us)(__float_as_uint(f) >> 16);
}
__device__ __forceinline__ float bf16tof(us u) {
    return __uint_as_float(((unsigned int)u) << 16);
}
__device__ __forceinline__ us bf16rtn(float f) {
    unsigned u = __float_as_uint(f);
    return (us)((u + 0x7FFFu + ((u >> 16) & 1u)) >> 16);
}

// ---------- CSR sort-by-row ----------
__global__ void k_cnt(const int* __restrict__ rows, int* __restrict__ cnti, int E) {
    int i = blockIdx.x * 256 + threadIdx.x;
    if (i < E) atomicAdd(&cnti[rows[i]], 1);
}

__global__ void k_scan(const int* __restrict__ cnti, int* __restrict__ base, int N) {
    __shared__ int part[256];
    int t = threadIdx.x;
    int chunk = (N + 255) / 256;
    int lo = t * chunk, hi = lo + chunk < N ? lo + chunk : N;
    int s = 0;
    for (int i = lo; i < hi; ++i) s += cnti[i];
    part[t] = s;
    __syncthreads();
    for (int off = 1; off < 256; off <<= 1) {
        int v = (t >= off) ? part[t - off] : 0;
        __syncthreads();
        part[t] += v;
        __syncthreads();
    }
    int run = (t == 0) ? 0 : part[t - 1];
    for (int i = lo; i < hi; ++i) { base[i] = run; run += cnti[i]; }
}

__global__ void k_scatter(const int* __restrict__ rows, const int* __restrict__ cols,
                          const float* __restrict__ eattr,
                          const int* __restrict__ base, int* __restrict__ fill,
                          int* __restrict__ srow, int* __restrict__ scol,
                          float* __restrict__ sea, int E) {
    int e = blockIdx.x * 256 + threadIdx.x;
    if (e >= E) return;
    int r = rows[e];
    int pos = base[r] + atomicAdd(&fill[r], 1);
    srow[pos] = r;
    scol[pos] = cols[e];
    sea[pos * 2 + 0] = eattr[(size_t)e * 2 + 0];
    sea[pos * 2 + 1] = eattr[(size_t)e * 2 + 1];
}

__global__ void k_embed(const float* __restrict__ hin, const float* __restrict__ w,
                        const float* __restrict__ b, float* __restrict__ hout, int N) {
    int idx = blockIdx.x * 256 + threadIdx.x;
    if (idx >= N * HID) return;
    int n = idx >> 7, j = idx & 127;
    float s = b[j];
    const float* hr = &hin[n * 6];
#pragma unroll
    for (int k = 0; k < 6; ++k) s += hr[k] * w[k * HID + j];
    hout[idx] = s;
}

// pack weights TRANSPOSED as MFMA A-fragments.
// w1/w2: split hi(trunc)+lo planes; c1: RTN hi only.
// A[m=n_out within 32-tile][k]: lane owns m=lane&31, k=(lane>>5)*8+j.
// o = ((kc*4+t4)*64+lane)*8 + j; w1: 17 kc (k<259 weights, k==259 bias);
// w2/c1: 9 kc (k<128 weights, k==128 bias). Plus coefficient packs matching C rows.
__global__ void k_pack_a(const float* __restrict__ ew1, const float* __restrict__ eb1,
                         const float* __restrict__ ew2, const float* __restrict__ eb2,
                         const float* __restrict__ cw1, const float* __restrict__ cb1,
                         const float* __restrict__ aw, const float* __restrict__ cw2,
                         us* __restrict__ w1a, us* __restrict__ w1al,
                         us* __restrict__ w2a, us* __restrict__ w2al,
                         us* __restrict__ c1a,
                         float* __restrict__ awp, float* __restrict__ cw2p) {
    int idx = blockIdx.x * 256 + threadIdx.x;
    const int total = 4 * 35 * 2048;
    if (idx < total) {
        int l = idx / (35 * 2048);
        int off = idx % (35 * 2048);
        int mat, kc, c;
        if (off < 17 * 2048) { mat = 0; kc = off >> 11; c = off & 2047; }
        else if (off < 26 * 2048) { mat = 1; int o2 = off - 17 * 2048; kc = o2 >> 11; c = o2 & 2047; }
        else { mat = 2; int o2 = off - 26 * 2048; kc = o2 >> 11; c = o2 & 2047; }
        int t4 = c >> 9, lane = (c >> 3) & 63, j = c & 7;
        int k = kc * 16 + ((lane >> 5) << 3) + j;
        int n = (t4 << 5) + (lane & 31);
        float f = 0.f;
        if (mat == 0) {
            if (k < 259) f = ew1[(size_t)l * 33152 + k * 128 + n];
            else if (k == 259) f = eb1[l * 128 + n];
        } else if (mat == 1) {
            if (k < 128) f = ew2[(size_t)l * 16384 + k * 128 + n];
            else if (k == 128) f = eb2[l * 128 + n];
        } else {
            if (k < 128) f = cw1[(size_t)l * 16384 + k * 128 + n];
            else if (k == 128) f = cb1[l * 128 + n];
        }
        int o = ((kc * 4 + t4) * 64 + lane) * 8 + j;
        if (mat == 0) {
            us hi = bf16trunc(f);
            w1a[(size_t)l * 34816 + o] = hi;
            w1al[(size_t)l * 34816 + o] = bf16trunc(f - bf16tof(hi));
        } else if (mat == 1) {
            us hi = bf16trunc(f);
            w2a[(size_t)l * 18432 + o] = hi;
            w2al[(size_t)l * 18432 + o] = bf16trunc(f - bf16tof(hi));
        } else {
            c1a[(size_t)l * 18432 + o] = bf16rtn(f);
        }
    } else if (idx < total + 1024) {
        int q = idx - total;
        int l = q >> 8;
        int rest = q & 255;
        int tb = rest >> 7, i = rest & 127;
        int half = i >> 6, qq = i & 63;
        int t4 = qq >> 4, reg = qq & 15;
        int n = (t4 << 5) + (reg & 3) + ((reg >> 2) << 3) + (half << 2);
        if (tb == 0) awp[l * 128 + i] = aw[l * 128 + n];
        else         cw2p[l * 128 + i] = cw2[l * 128 + n];
    }
}

__global__ void k_prep_h(const float* __restrict__ h, us* __restrict__ hhi,
                         us* __restrict__ hlo, int N) {
    int idx = blockIdx.x * 256 + threadIdx.x;
    if (idx >= N * HID) return;
    float f = h[idx];
    us hi = bf16trunc(f);
    hhi[idx] = hi;
    hlo[idx] = bf16trunc(f - bf16tof(hi));
}

// Edge kernel: D[n][edge], weights=A (global L2), edges=B.
// Wave = 32 edges, 4 independent waves/block, acts via per-wave-private LDS.
// No __syncthreads. GEMM1/2: 3-term split; GEMM3: 2-term; m streamed fp32.
__global__ __launch_bounds__(256, 2) void k_edge_mfma(
    const us* __restrict__ hhi, const us* __restrict__ hlo,
    const float* __restrict__ x,
    const int* __restrict__ srow, const int* __restrict__ scol,
    const float* __restrict__ sea,
    const us* __restrict__ w1a, const us* __restrict__ w1al,
    const us* __restrict__ w2a, const us* __restrict__ w2al,
    const us* __restrict__ c1a,
    const float* __restrict__ awp, const float* __restrict__ cw2p,
    const float* __restrict__ ab,
    float* __restrict__ mT, float* __restrict__ aggx, int E)
{
    __shared__ __align__(16) us tHi[4][32][PAD];
    __shared__ __align__(16) us tLo[4][32][PAD];

    const int t = threadIdx.x;
    const int wv = t >> 6, lane = t & 63;
    const int l5 = lane >> 5, ll = lane & 31;
    const int e = (blockIdx.x * 4 + wv) * 32 + ll;
    const int ec = e < E ? e : E - 1;

    const int rN = srow[ec], cN = scol[ec];
    float dx = x[rN * 3 + 0] - x[cN * 3 + 0];
    float dy = x[rN * 3 + 1] - x[cN * 3 + 1];
    float dz = x[rN * 3 + 2] - x[cN * 3 + 2];
    float rad = dx * dx + dy * dy + dz * dz;
    float ea0 = sea[(size_t)ec * 2 + 0];
    float ea1 = sea[(size_t)ec * 2 + 1];

    // virtual B chunk for GEMM1 tail: k=256..259 = [rad, ea0, ea1, 1] (l5==0 half)
    bf16x8 bvh = (bf16x8)(short)0, bvl = (bf16x8)(short)0;
    if (l5 == 0) {
        float vv[4] = {rad, ea0, ea1, 1.0f};
#pragma unroll
        for (int i = 0; i < 4; ++i) {
            us h = bf16trunc(vv[i]);
            bvh[i] = (short)h;
            bvl[i] = (short)bf16trunc(vv[i] - bf16tof(h));
        }
    }
    // bias-only chunk: B=1 at k-slot 0 of l5==0
    bf16x8 bone = (bf16x8)(short)0;
    if (l5 == 0) bone[0] = (short)0x3F80;

    us* myHi = &tHi[wv][0][0];
    us* myLo = &tLo[wv][0][0];

    // ---- GEMM1: t1[n][e] over K=256 gathered h (+ virtual tail), 3-term ----
    {
        f32x16 acc[4];
#pragma unroll
        for (int i = 0; i < 4; ++i)
#pragma unroll
            for (int j = 0; j < 16; ++j) acc[i][j] = 0.f;
#pragma unroll
        for (int kc = 0; kc < 16; ++kc) {
            int node = (kc < 8) ? rN : cN;
            int ko = ((kc & 7) << 4) + (l5 << 3);
            bf16x8 bh = *(const bf16x8*)(hhi + (size_t)node * HID + ko);
            bf16x8 bl = *(const bf16x8*)(hlo + (size_t)node * HID + ko);
#pragma unroll
            for (int t4 = 0; t4 < 4; ++t4) {
                bf16x8 a  = *(const bf16x8*)(w1a  + ((kc * 4 + t4) * 64 + lane) * 8);
                bf16x8 al = *(const bf16x8*)(w1al + ((kc * 4 + t4) * 64 + lane) * 8);
                acc[t4] = __builtin_amdgcn_mfma_f32_32x32x16_bf16(a,  bh, acc[t4], 0, 0, 0);
                acc[t4] = __builtin_amdgcn_mfma_f32_32x32x16_bf16(al, bh, acc[t4], 0, 0, 0);
                acc[t4] = __builtin_amdgcn_mfma_f32_32x32x16_bf16(a,  bl, acc[t4], 0, 0, 0);
            }
        }
#pragma unroll
        for (int t4 = 0; t4 < 4; ++t4) {
            bf16x8 a  = *(const bf16x8*)(w1a  + ((16 * 4 + t4) * 64 + lane) * 8);
            bf16x8 al = *(const bf16x8*)(w1al + ((16 * 4 + t4) * 64 + lane) * 8);
            acc[t4] = __builtin_amdgcn_mfma_f32_32x32x16_bf16(a,  bvh, acc[t4], 0, 0, 0);
            acc[t4] = __builtin_amdgcn_mfma_f32_32x32x16_bf16(al, bvh, acc[t4], 0, 0, 0);
            acc[t4] = __builtin_amdgcn_mfma_f32_32x32x16_bf16(a,  bvl, acc[t4], 0, 0, 0);
        }
        // epilogue1: silu + split -> LDS (packed b64 writes, 4 consecutive n)
#pragma unroll
        for (int t4 = 0; t4 < 4; ++t4)
#pragma unroll
            for (int q = 0; q < 4; ++q) {
                int n0 = t4 * 32 + q * 8 + l5 * 4;
                unsigned hp[2], lp[2];
#pragma unroll
                for (int c = 0; c < 2; ++c) {
                    float v0 = silu_f(acc[t4][q * 4 + 2 * c]);
                    float v1 = silu_f(acc[t4][q * 4 + 2 * c + 1]);
                    unsigned u0 = __float_as_uint(v0), u1 = __float_as_uint(v1);
                    hp[c] = (u0 >> 16) | (u1 & 0xFFFF0000u);
                    float r0 = v0 - __uint_as_float(u0 & 0xFFFF0000u);
                    float r1 = v1 - __uint_as_float(u1 & 0xFFFF0000u);
                    lp[c] = (__float_as_uint(r0) >> 16) | (__float_as_uint(r1) & 0xFFFF0000u);
                }
                *(uint2*)(myHi + ll * PAD + n0) = make_uint2(hp[0], hp[1]);
                *(uint2*)(myLo + ll * PAD + n0) = make_uint2(lp[0], lp[1]);
            }
    }

    // ---- GEMM2: t2[n][e] = w2^T @ t1 (acts from LDS), 3-term ----
    f32x16 acc2[4];
#pragma unroll
    for (int i = 0; i < 4; ++i)
#pragma unroll
        for (int j = 0; j < 16; ++j) acc2[i][j] = 0.f;
#pragma unroll
    for (int kc = 0; kc < 8; ++kc) {
        bf16x8 bh = *(const bf16x8*)(myHi + ll * PAD + kc * 16 + l5 * 8);
        bf16x8 bl = *(const bf16x8*)(myLo + ll * PAD + kc * 16 + l5 * 8);
#pragma unroll
        for (int t4 = 0; t4 < 4; ++t4) {
            bf16x8 a  = *(const bf16x8*)(w2a  + ((kc * 4 + t4) * 64 + lane) * 8);
            bf16x8 al = *(const bf16x8*)(w2al + ((kc * 4 + t4) * 64 + lane) * 8);
            acc2[t4] = __builtin_amdgcn_mfma_f32_32x32x16_bf16(a,  bh, acc2[t4], 0, 0, 0);
            acc2[t4] = __builtin_amdgcn_mfma_f32_32x32x16_bf16(al, bh, acc2[t4], 0, 0, 0);
            acc2[t4] = __builtin_amdgcn_mfma_f32_32x32x16_bf16(a,  bl, acc2[t4], 0, 0, 0);
        }
    }
#pragma unroll
    for (int t4 = 0; t4 < 4; ++t4) {   // bias chunk (hi+lo, bone)
        bf16x8 a  = *(const bf16x8*)(w2a  + ((8 * 4 + t4) * 64 + lane) * 8);
        bf16x8 al = *(const bf16x8*)(w2al + ((8 * 4 + t4) * 64 + lane) * 8);
        acc2[t4] = __builtin_amdgcn_mfma_f32_32x32x16_bf16(a,  bone, acc2[t4], 0, 0, 0);
        acc2[t4] = __builtin_amdgcn_mfma_f32_32x32x16_bf16(al, bone, acc2[t4], 0, 0, 0);
    }

    // ---- attention gate (per-lane dot over own n's + one shfl) ----
    float att;
    {
        float p = 0.f;
        const float4* aw4 = (const float4*)(awp + (l5 << 6));
#pragma unroll
        for (int t4 = 0; t4 < 4; ++t4)
#pragma unroll
            for (int rq = 0; rq < 4; ++rq) {
                float4 cv = aw4[t4 * 4 + rq];
                p += cv.x * silu_f(acc2[t4][rq * 4 + 0]);
                p += cv.y * silu_f(acc2[t4][rq * 4 + 1]);
                p += cv.z * silu_f(acc2[t4][rq * 4 + 2]);
                p += cv.w * silu_f(acc2[t4][rq * 4 + 3]);
            }
        p += __shfl_xor(p, 32);
        att = sigmoid_f(p + ab[0]);
    }

    // ---- epilogue2: m = silu(t2)*att -> LDS hi+lo + fp32 mT stream ----
#pragma unroll
    for (int t4 = 0; t4 < 4; ++t4)
#pragma unroll
        for (int q = 0; q < 4; ++q) {
            int n0 = t4 * 32 + q * 8 + l5 * 4;
            float mv[4];
            us mh[4], mlo[4];
#pragma unroll
            for (int c = 0; c < 4; ++c) {
                mv[c] = silu_f(acc2[t4][q * 4 + c]) * att;
                mh[c] = bf16trunc(mv[c]);
                mlo[c] = bf16trunc(mv[c] - bf16tof(mh[c]));
            }
            *(uint2*)(myHi + ll * PAD + n0) = make_uint2(
                (unsigned)mh[0] | ((unsigned)mh[1] << 16),
                (unsigned)mh[2] | ((unsigned)mh[3] << 16));
            *(uint2*)(myLo + ll * PAD + n0) = make_uint2(
                (unsigned)mlo[0] | ((unsigned)mlo[1] << 16),
                (unsigned)mlo[2] | ((unsigned)mlo[3] << 16));
            if (e < E) {
#pragma unroll
                for (int c = 0; c < 4; ++c)
                    mT[(size_t)(n0 + c) * E + e] = mv[c];
            }
        }

    // ---- GEMM3 (2-term): u = c1^T @ m ----
    f32x16 acc3[4];
#pragma unroll
    for (int i = 0; i < 4; ++i)
#pragma unroll
        for (int j = 0; j < 16; ++j) acc3[i][j] = 0.f;
#pragma unroll
    for (int kc = 0; kc < 8; ++kc) {
        bf16x8 bh = *(const bf16x8*)(myHi + ll * PAD + kc * 16 + l5 * 8);
        bf16x8 bl = *(const bf16x8*)(myLo + ll * PAD + kc * 16 + l5 * 8);
#pragma unroll
        for (int t4 = 0; t4 < 4; ++t4) {
            bf16x8 a = *(const bf16x8*)(c1a + ((kc * 4 + t4) * 64 + lane) * 8);
            acc3[t4] = __builtin_amdgcn_mfma_f32_32x32x16_bf16(a, bh, acc3[t4], 0, 0, 0);
            acc3[t4] = __builtin_amdgcn_mfma_f32_32x32x16_bf16(a, bl, acc3[t4], 0, 0, 0);
        }
    }
#pragma unroll
    for (int t4 = 0; t4 < 4; ++t4) {   // bias chunk
        bf16x8 a = *(const bf16x8*)(c1a + ((8 * 4 + t4) * 64 + lane) * 8);
        acc3[t4] = __builtin_amdgcn_mfma_f32_32x32x16_bf16(a, bone, acc3[t4], 0, 0, 0);
    }

    // ---- wc + aggx atomics ----
    {
        float wc = 0.f;
        const float4* cw4 = (const float4*)(cw2p + (l5 << 6));
#pragma unroll
        for (int t4 = 0; t4 < 4; ++t4)
#pragma unroll
            for (int rq = 0; rq < 4; ++rq) {
                float4 cv = cw4[t4 * 4 + rq];
                wc += cv.x * silu_f(acc3[t4][rq * 4 + 0]);
                wc += cv.y * silu_f(acc3[t4][rq * 4 + 1]);
                wc += cv.z * silu_f(acc3[t4][rq * 4 + 2]);
                wc += cv.w * silu_f(acc3[t4][rq * 4 + 3]);
            }
        wc += __shfl_xor(wc, 32);
        if (l5 == 0 && e < E) {
            atomicAdd(&aggx[rN * 3 + 0], dx * wc);
            atomicAdd(&aggx[rN * 3 + 1], dy * wc);
            atomicAdd(&aggx[rN * 3 + 2], dz * wc);
        }
    }
}

// 64 nodes per block; agg_h = CSR sum over fp32 mT[n][e]
__global__ __launch_bounds__(256, 2) void k_node(
    float* __restrict__ h, const float* __restrict__ mT,
    const int* __restrict__ basei,
    const float* __restrict__ aggx, const int* __restrict__ cnti,
    float* __restrict__ x, float* __restrict__ vel,
    const float* __restrict__ vw1, const float* __restrict__ vb1,
    const float* __restrict__ vw2, const float* __restrict__ vb2,
    const float* __restrict__ nw1, const float* __restrict__ nb1,
    const float* __restrict__ nw2, const float* __restrict__ nb2,
    int N, int E)
{
    __shared__ __align__(16) float BH[64][132];
    __shared__ __align__(16) float BG[64][132];
    const int t = threadIdx.x;
    const int tx = t & 15, ty = t >> 4;
    const int n0 = blockIdx.x * 64;

    for (int idx = t; idx < 64 * 32; idx += 256) {
        int r = idx >> 5, c4 = idx & 31;
        int n = n0 + r;
        float4 v0 = make_float4(0.f, 0.f, 0.f, 0.f);
        if (n < N) v0 = *(const float4*)&h[(size_t)n * HID + c4 * 4];
        *(float4*)&BH[r][c4 * 4] = v0;
    }
#pragma unroll
    for (int i = 0; i < 4; ++i) {
        int n = n0 + ty * 4 + i;
        float s[8];
#pragma unroll
        for (int j = 0; j < 8; ++j) s[j] = 0.f;
        if (n < N) {
            int ebg = basei[n], ee = ebg + cnti[n];
            for (int ed = ebg; ed < ee; ++ed) {
#pragma unroll
                for (int j = 0; j < 8; ++j)
                    s[j] += mT[(size_t)(tx * 8 + j) * E + ed];
            }
        }
#pragma unroll
        for (int j = 0; j < 8; ++j) BG[ty * 4 + i][tx * 8 + j] = s[j];
    }
    __syncthreads();

    {
        float acc[4][8];
#pragma unroll
        for (int i = 0; i < 4; ++i)
#pragma unroll
            for (int j = 0; j < 8; ++j) acc[i][j] = 0.f;
        const float* wp = &vw1[tx * 8];
#pragma unroll 4
        for (int k = 0; k < HID; ++k) {
            float4 w0 = *(const float4*)&wp[k * HID];
            float4 w1v = *(const float4*)&wp[k * HID + 4];
            float wvv[8] = {w0.x, w0.y, w0.z, w0.w, w1v.x, w1v.y, w1v.z, w1v.w};
            float av[4];
#pragma unroll
            for (int i = 0; i < 4; ++i) av[i] = BH[ty * 4 + i][k];
#pragma unroll
            for (int i = 0; i < 4; ++i)
#pragma unroll
                for (int j = 0; j < 8; ++j) acc[i][j] += av[i] * wvv[j];
        }
        float bb[8], w2v[8];
#pragma unroll
        for (int j = 0; j < 8; ++j) { bb[j] = vb1[tx * 8 + j]; w2v[j] = vw2[tx * 8 + j]; }
        float vb20 = vb2[0];
#pragma unroll
        for (int i = 0; i < 4; ++i) {
            float p = 0.f;
#pragma unroll
            for (int j = 0; j < 8; ++j) p += silu_f(acc[i][j] + bb[j]) * w2v[j];
            p += __shfl_xor(p, 1);
            p += __shfl_xor(p, 2);
            p += __shfl_xor(p, 4);
            p += __shfl_xor(p, 8);
            float vs = p + vb20;
            if (tx == 0) {
                int n = n0 + ty * 4 + i;
                if (n < N) {
                    float cc = fmaxf((float)cnti[n], 1.0f);
#pragma unroll
                    for (int d = 0; d < 3; ++d) {
                        float vn = vs * vel[n * 3 + d];
                        float xn = x[n * 3 + d] + aggx[n * 3 + d] / cc + vn;
                        vel[n * 3 + d] = vn;
                        x[n * 3 + d] = xn;
                    }
                }
            }
        }
    }

    float acc2[4][8];
#pragma unroll
    for (int i = 0; i < 4; ++i)
#pragma unroll
        for (int j = 0; j < 8; ++j) acc2[i][j] = 0.f;
    {
        const float* wp = &nw1[tx * 8];
#pragma unroll 4
        for (int k = 0; k < HID; ++k) {
            float4 w0 = *(const float4*)&wp[k * HID];
            float4 w1v = *(const float4*)&wp[k * HID + 4];
            float wvv[8] = {w0.x, w0.y, w0.z, w0.w, w1v.x, w1v.y, w1v.z, w1v.w};
            float av[4];
#pragma unroll
            for (int i = 0; i < 4; ++i) av[i] = BH[ty * 4 + i][k];
#pragma unroll
            for (int i = 0; i < 4; ++i)
#pragma unroll
                for (int j = 0; j < 8; ++j) acc2[i][j] += av[i] * wvv[j];
        }
        const float* wp2 = &nw1[128 * HID + tx * 8];
#pragma unroll 4
        for (int k = 0; k < HID; ++k) {
            float4 w0 = *(const float4*)&wp2[k * HID];
            float4 w1v = *(const float4*)&wp2[k * HID + 4];
            float wvv[8] = {w0.x, w0.y, w0.z, w0.w, w1v.x, w1v.y, w1v.z, w1v.w};
            float av[4];
#pragma unroll
            for (int i = 0; i < 4; ++i) av[i] = BG[ty * 4 + i][k];
#pragma unroll
            for (int i = 0; i < 4; ++i)
#pragma unroll
                for (int j = 0; j < 8; ++j) acc2[i][j] += av[i] * wvv[j];
        }
    }
    __syncthreads();
    {
        float bb[8];
#pragma unroll
        for (int j = 0; j < 8; ++j) bb[j] = nb1[tx * 8 + j];
#pragma unroll
        for (int i = 0; i < 4; ++i)
#pragma unroll
            for (int j = 0; j < 8; ++j)
                BH[ty * 4 + i][tx * 8 + j] = silu_f(acc2[i][j] + bb[j]);
    }
    __syncthreads();
    float acc3[4][8];
#pragma unroll
    for (int i = 0; i < 4; ++i)
#pragma unroll
        for (int j = 0; j < 8; ++j) acc3[i][j] = 0.f;
    {
        const float* wp = &nw2[tx * 8];
#pragma unroll 4
        for (int k = 0; k < HID; ++k) {
            float4 w0 = *(const float4*)&wp[k * HID];
            float4 w1v = *(const float4*)&wp[k * HID + 4];
            float wvv[8] = {w0.x, w0.y, w0.z, w0.w, w1v.x, w1v.y, w1v.z, w1v.w};
            float av[4];
#pragma unroll
            for (int i = 0; i < 4; ++i) av[i] = BH[ty * 4 + i][k];
#pragma unroll
            for (int i = 0; i < 4; ++i)
#pragma unroll
                for (int j = 0; j < 8; ++j) acc3[i][j] += av[i] * wvv[j];
        }
    }
    {
        float bb[8];
#pragma unroll
        for (int j = 0; j < 8; ++j) bb[j] = nb2[tx * 8 + j];
#pragma unroll
        for (int i = 0; i < 4; ++i) {
            int n = n0 + ty * 4 + i;
            if (n < N) {
#pragma unroll
                for (int j = 0; j < 8; ++j)
                    h[(size_t)n * HID + tx * 8 + j] = acc3[i][j] + bb[j];
            }
        }
    }
}

__global__ void k_proj(const float* __restrict__ h, const float* __restrict__ pw,
                       const float* __restrict__ pb, float* __restrict__ out, int N) {
    int idx = blockIdx.x * 256 + threadIdx.x;
    if (idx >= N * 3) return;
    int n = idx / 3, p = idx % 3;
    float s = pb[p];
    const float* hr = &h[(size_t)n * HID];
#pragma unroll 8
    for (int k = 0; k < HID; ++k) s += hr[k] * pw[k * 3 + p];
    out[idx] = s;
}

extern "C" void kernel_launch(void* const* d_in, const int* in_sizes, int n_in,
                              void* d_out, int out_size, void* d_ws, size_t ws_size,
                              hipStream_t stream)
{
    const float* h_in  = (const float*)d_in[0];
    const float* x_in  = (const float*)d_in[1];
    const float* v_in  = (const float*)d_in[2];
    const float* eattr = (const float*)d_in[3];
    const int*   edges = (const int*)d_in[4];
    const float* emb_w = (const float*)d_in[5];
    const float* emb_b = (const float*)d_in[6];
    const float* ew1   = (const float*)d_in[7];
    const float* eb1   = (const float*)d_in[8];
    const float* ew2   = (const float*)d_in[9];
    const float* eb2   = (const float*)d_in[10];
    const float* aw    = (const float*)d_in[11];
    const float* ab    = (const float*)d_in[12];
    const float* nw1   = (const float*)d_in[13];
    const float* nb1   = (const float*)d_in[14];
    const float* nw2   = (const float*)d_in[15];
    const float* nb2   = (const float*)d_in[16];
    const float* cw1   = (const float*)d_in[17];
    const float* cb1   = (const float*)d_in[18];
    const float* cw2   = (const float*)d_in[19];
    const float* vw1   = (const float*)d_in[20];
    const float* vb1   = (const float*)d_in[21];
    const float* vw2   = (const float*)d_in[22];
    const float* vb2   = (const float*)d_in[23];
    const float* pw    = (const float*)d_in[24];
    const float* pb    = (const float*)d_in[25];

    const int N = in_sizes[0] / 6;
    const int E = in_sizes[4] / 2;
    const int* rows = edges;
    const int* cols = edges + E;

    float* ws   = (float*)d_ws;
    float* hbuf = ws;  ws += (size_t)N * HID;
    float* aggx = ws;  ws += (size_t)N * 3;
    float* xb   = ws;  ws += (size_t)N * 3;
    float* vb   = ws;  ws += (size_t)N * 3;
    float* sea  = ws;  ws += (size_t)E * 2;
    float* awp  = ws;  ws += 4 * 128;
    float* cw2p = ws;  ws += 4 * 128;
    float* mT   = ws;  ws += (size_t)E * HID;   // 164 MB
    int* wi = (int*)ws;
    int* cnti = wi;  wi += N;
    int* basei = wi; wi += N;
    int* fill = wi;  wi += N;
    int* srow = wi;  wi += E;
    int* scol = wi;  wi += E;
    us* usp = (us*)wi;
    us* hhi = usp;   usp += (size_t)N * HID;
    us* hlo = usp;   usp += (size_t)N * HID;
    us* w1a = usp;   usp += 4 * 34816;
    us* w1al = usp;  usp += 4 * 34816;
    us* w2a = usp;   usp += 4 * 18432;
    us* w2al = usp;  usp += 4 * 18432;
    us* c1a = usp;   usp += 4 * 18432;
    float* outp = (float*)d_out;

    hipMemcpyAsync(xb, x_in, (size_t)N * 3 * sizeof(float), hipMemcpyDeviceToDevice, stream);
    hipMemcpyAsync(vb, v_in, (size_t)N * 3 * sizeof(float), hipMemcpyDeviceToDevice, stream);
    hipMemsetAsync(cnti, 0, N * sizeof(int), stream);
    hipMemsetAsync(fill, 0, N * sizeof(int), stream);
    k_cnt<<<(E + 255) / 256, 256, 0, stream>>>(rows, cnti, E);
    k_scan<<<1, 256, 0, stream>>>(cnti, basei, N);
    k_scatter<<<(E + 255) / 256, 256, 0, stream>>>(rows, cols, eattr, basei, fill,
                                                   srow, scol, sea, E);
    k_pack_a<<<(4 * 35 * 2048 + 1024 + 255) / 256, 256, 0, stream>>>(
        ew1, eb1, ew2, eb2, cw1, cb1, aw, cw2,
        w1a, w1al, w2a, w2al, c1a, awp, cw2p);
    k_embed<<<(N * HID + 255) / 256, 256, 0, stream>>>(h_in, emb_w, emb_b, hbuf, N);

    for (int l = 0; l < 4; ++l) {
        k_prep_h<<<(N * HID + 255) / 256, 256, 0, stream>>>(hbuf, hhi, hlo, N);
        hipMemsetAsync(aggx, 0, (size_t)N * 3 * sizeof(float), stream);
        k_edge_mfma<<<(E + 127) / 128, 256, 0, stream>>>(
            hhi, hlo, xb, srow, scol, sea,
            w1a + (size_t)l * 34816, w1al + (size_t)l * 34816,
            w2a + (size_t)l * 18432, w2al + (size_t)l * 18432,
            c1a + (size_t)l * 18432,
            awp + l * 128, cw2p + l * 128, ab + l,
            mT, aggx, E);
        k_node<<<(N + 63) / 64, 256, 0, stream>>>(
            hbuf, mT, basei, aggx, cnti, xb, vb,
            vw1 + (size_t)l * HID * HID, vb1 + l * HID, vw2 + l * HID, vb2 + l,
            nw1 + (size_t)l * 2 * HID * HID, nb1 + l * HID,
            nw2 + (size_t)l * HID * HID, nb2 + l * HID, N, E);
    }
    k_proj<<<(N * 3 + 255) / 256, 256, 0, stream>>>(hbuf, pw, pb, outp, N);
    hipMemcpyAsync(outp + (size_t)N * 3, xb, (size_t)N * 3 * sizeof(float), hipMemcpyDeviceToDevice, stream);
    hipMemcpyAsync(outp + (size_t)N * 6, vb, (size_t)N * 3 * sizeof(float), hipMemcpyDeviceToDevice, stream);
}

// Round 9
// 1557.106 us; speedup vs baseline: 2.2607x; 2.2607x over previous
//
#include <hip/hip_runtime.h>
#include <math.h>

#define HID 128
#define PAD 138

typedef __attribute__((ext_vector_type(8))) short bf16x8;
typedef __attribute__((ext_vector_type(16))) float f32x16;
typedef unsigned short us;

__device__ __forceinline__ float silu_f(float v) {
    return v / (1.0f + __expf(-v));
}
__device__ __forceinline__ float sigmoid_f(float v) {
    return 1.0f / (1.0f + __expf(-v));
}
__device__ __forceinline__ us bf16trunc(float f) {
    return (us)(__float_as_uint(f) >> 16);
}
__device__ __forceinline__ float bf16tof(us u) {
    return __uint_as_float(((unsigned int)u) << 16);
}
__device__ __forceinline__ us bf16rtn(float f) {
    unsigned u = __float_as_uint(f);
    return (us)((u + 0x7FFFu + ((u >> 16) & 1u)) >> 16);
}

// ---------- CSR sort-by-row ----------
__global__ void k_cnt(const int* __restrict__ rows, int* __restrict__ cnti, int E) {
    int i = blockIdx.x * 256 + threadIdx.x;
    if (i < E) atomicAdd(&cnti[rows[i]], 1);
}

__global__ void k_scan(const int* __restrict__ cnti, int* __restrict__ base, int N) {
    __shared__ int part[256];
    int t = threadIdx.x;
    int chunk = (N + 255) / 256;
    int lo = t * chunk, hi = lo + chunk < N ? lo + chunk : N;
    int s = 0;
    for (int i = lo; i < hi; ++i) s += cnti[i];
    part[t] = s;
    __syncthreads();
    for (int off = 1; off < 256; off <<= 1) {
        int v = (t >= off) ? part[t - off] : 0;
        __syncthreads();
        part[t] += v;
        __syncthreads();
    }
    int run = (t == 0) ? 0 : part[t - 1];
    for (int i = lo; i < hi; ++i) { base[i] = run; run += cnti[i]; }
}

__global__ void k_scatter(const int* __restrict__ rows, const int* __restrict__ cols,
                          const float* __restrict__ eattr,
                          const int* __restrict__ base, int* __restrict__ fill,
                          int* __restrict__ srow, int* __restrict__ scol,
                          float* __restrict__ sea, int E) {
    int e = blockIdx.x * 256 + threadIdx.x;
    if (e >= E) return;
    int r = rows[e];
    int pos = base[r] + atomicAdd(&fill[r], 1);
    srow[pos] = r;
    scol[pos] = cols[e];
    sea[pos * 2 + 0] = eattr[(size_t)e * 2 + 0];
    sea[pos * 2 + 1] = eattr[(size_t)e * 2 + 1];
}

__global__ void k_embed(const float* __restrict__ hin, const float* __restrict__ w,
                        const float* __restrict__ b, float* __restrict__ hout, int N) {
    int idx = blockIdx.x * 256 + threadIdx.x;
    if (idx >= N * HID) return;
    int n = idx >> 7, j = idx & 127;
    float s = b[j];
    const float* hr = &hin[n * 6];
#pragma unroll
    for (int k = 0; k < 6; ++k) s += hr[k] * w[k * HID + j];
    hout[idx] = s;
}

// Per-node hoist: P[n][0:128] = h[n]@ew1[0:128], P[n][128:256] = h[n]@ew1[128:256]
__global__ __launch_bounds__(256, 2) void k_prep_p(
    const float* __restrict__ h, const float* __restrict__ ew1,
    float* __restrict__ P, int N)
{
    __shared__ __align__(16) float BH[64][132];
    const int t = threadIdx.x;
    const int tx = t & 31, ty = t >> 5;   // tx: 32 out-groups of 8 (256); ty: 8 node-groups of 8
    const int n0 = blockIdx.x * 64;

    for (int idx = t; idx < 64 * 32; idx += 256) {
        int r = idx >> 5, c4 = idx & 31;
        int n = n0 + r;
        float4 v0 = make_float4(0.f, 0.f, 0.f, 0.f);
        if (n < N) v0 = *(const float4*)&h[(size_t)n * HID + c4 * 4];
        *(float4*)&BH[r][c4 * 4] = v0;
    }
    __syncthreads();

    const float* wbase = (tx < 16) ? (ew1 + tx * 8) : (ew1 + 128 * HID + (tx - 16) * 8);
    float acc[8][8];
#pragma unroll
    for (int i = 0; i < 8; ++i)
#pragma unroll
        for (int j = 0; j < 8; ++j) acc[i][j] = 0.f;
#pragma unroll 4
    for (int k = 0; k < HID; ++k) {
        float4 w0 = *(const float4*)&wbase[k * HID];
        float4 w1 = *(const float4*)&wbase[k * HID + 4];
        float wv[8] = {w0.x, w0.y, w0.z, w0.w, w1.x, w1.y, w1.z, w1.w};
        float av[8];
#pragma unroll
        for (int i = 0; i < 8; ++i) av[i] = BH[ty * 8 + i][k];
#pragma unroll
        for (int i = 0; i < 8; ++i)
#pragma unroll
            for (int j = 0; j < 8; ++j) acc[i][j] += av[i] * wv[j];
    }
#pragma unroll
    for (int i = 0; i < 8; ++i) {
        int n = n0 + ty * 8 + i;
        if (n < N) {
#pragma unroll
            for (int j = 0; j < 8; ++j)
                P[(size_t)n * 256 + tx * 8 + j] = acc[i][j];
        }
    }
}

// pack: w1 tail chunk (k=256..271: rad/ea/bias rows) hi+lo; w2 hi+lo; c1 RTN hi.
// A-fragment: lane owns m=lane&31, k=(lane>>5)*8+j; o=((kc*4+t4)*64+lane)*8+j.
__global__ void k_pack_a(const float* __restrict__ ew1, const float* __restrict__ eb1,
                         const float* __restrict__ ew2, const float* __restrict__ eb2,
                         const float* __restrict__ cw1, const float* __restrict__ cb1,
                         const float* __restrict__ aw, const float* __restrict__ cw2,
                         us* __restrict__ w1th, us* __restrict__ w1tl,
                         us* __restrict__ w2a, us* __restrict__ w2al,
                         us* __restrict__ c1a,
                         float* __restrict__ awp, float* __restrict__ cw2p) {
    int idx = blockIdx.x * 256 + threadIdx.x;
    const int per = 2048 + 18432 + 18432;
    const int total = 4 * per;
    if (idx < total) {
        int l = idx / per;
        int off = idx % per;
        if (off < 2048) {
            int t4 = off >> 9, lane = (off >> 3) & 63, j = off & 7;
            int k = 256 + ((lane >> 5) << 3) + j;
            int n = (t4 << 5) + (lane & 31);
            float f = 0.f;
            if (k < 259) f = ew1[(size_t)l * 33152 + k * 128 + n];
            else if (k == 259) f = eb1[l * 128 + n];
            us hi = bf16trunc(f);
            int o = (t4 * 64 + lane) * 8 + j;
            w1th[(size_t)l * 2048 + o] = hi;
            w1tl[(size_t)l * 2048 + o] = bf16trunc(f - bf16tof(hi));
        } else if (off < 2048 + 18432) {
            int o2 = off - 2048;
            int kc = o2 >> 11, c = o2 & 2047;
            int t4 = c >> 9, lane = (c >> 3) & 63, j = c & 7;
            int k = kc * 16 + ((lane >> 5) << 3) + j;
            int n = (t4 << 5) + (lane & 31);
            float f = 0.f;
            if (k < 128) f = ew2[(size_t)l * 16384 + k * 128 + n];
            else if (k == 128) f = eb2[l * 128 + n];
            us hi = bf16trunc(f);
            int o = ((kc * 4 + t4) * 64 + lane) * 8 + j;
            w2a[(size_t)l * 18432 + o] = hi;
            w2al[(size_t)l * 18432 + o] = bf16trunc(f - bf16tof(hi));
        } else {
            int o2 = off - 2048 - 18432;
            int kc = o2 >> 11, c = o2 & 2047;
            int t4 = c >> 9, lane = (c >> 3) & 63, j = c & 7;
            int k = kc * 16 + ((lane >> 5) << 3) + j;
            int n = (t4 << 5) + (lane & 31);
            float f = 0.f;
            if (k < 128) f = cw1[(size_t)l * 16384 + k * 128 + n];
            else if (k == 128) f = cb1[l * 128 + n];
            int o = ((kc * 4 + t4) * 64 + lane) * 8 + j;
            c1a[(size_t)l * 18432 + o] = bf16rtn(f);
        }
    } else if (idx < total + 1024) {
        int q = idx - total;
        int l = q >> 8;
        int rest = q & 255;
        int tb = rest >> 7, i = rest & 127;
        int half = i >> 6, qq = i & 63;
        int t4 = qq >> 4, reg = qq & 15;
        int n = (t4 << 5) + (reg & 3) + ((reg >> 2) << 3) + (half << 2);
        if (tb == 0) awp[l * 128 + i] = aw[l * 128 + n];
        else         cw2p[l * 128 + i] = cw2[l * 128 + n];
    }
}

// Edge kernel: D[n][edge]; t1 from per-node P gathers + 12-MFMA tail.
// GEMM2 3-term, GEMM3 2-term (c1 RTN). agg_h in-kernel via LDS column walk +
// run-flush atomics over sorted edges. No __syncthreads.
__global__ __launch_bounds__(256, 2) void k_edge_mfma(
    const float* __restrict__ P, const float* __restrict__ x,
    const int* __restrict__ srow, const int* __restrict__ scol,
    const float* __restrict__ sea,
    const us* __restrict__ w1th, const us* __restrict__ w1tl,
    const us* __restrict__ w2a, const us* __restrict__ w2al,
    const us* __restrict__ c1a,
    const float* __restrict__ awp, const float* __restrict__ cw2p,
    const float* __restrict__ ab,
    float* __restrict__ aggh, float* __restrict__ aggx, int E)
{
    __shared__ __align__(16) us tHi[4][32][PAD];
    __shared__ __align__(16) us tLo[4][32][PAD];
    __shared__ int sRW[4][32];

    const int t = threadIdx.x;
    const int wv = t >> 6, lane = t & 63;
    const int l5 = lane >> 5, ll = lane & 31;
    const int e = (blockIdx.x * 4 + wv) * 32 + ll;
    const int ec = e < E ? e : E - 1;

    const int rN = srow[ec], cN = scol[ec];
    float dx = x[rN * 3 + 0] - x[cN * 3 + 0];
    float dy = x[rN * 3 + 1] - x[cN * 3 + 1];
    float dz = x[rN * 3 + 2] - x[cN * 3 + 2];
    float rad = dx * dx + dy * dy + dz * dz;
    float ea0 = sea[(size_t)ec * 2 + 0];
    float ea1 = sea[(size_t)ec * 2 + 1];
    if (l5 == 0) sRW[wv][ll] = rN;

    // virtual B chunk: k-slots 0..3 (=rows 256..259: rad, ea0, ea1, bias) in l5==0 half
    bf16x8 bvh = (bf16x8)(short)0, bvl = (bf16x8)(short)0;
    if (l5 == 0) {
        float vv[4] = {rad, ea0, ea1, 1.0f};
#pragma unroll
        for (int i = 0; i < 4; ++i) {
            us h = bf16trunc(vv[i]);
            bvh[i] = (short)h;
            bvl[i] = (short)bf16trunc(vv[i] - bf16tof(h));
        }
    }
    bf16x8 bone = (bf16x8)(short)0;
    if (l5 == 0) bone[0] = (short)0x3F80;

    us* myHi = &tHi[wv][0][0];
    us* myLo = &tLo[wv][0][0];

    // ---- t1 = P[row] + P[col](+128) + tail-MFMA ----
    {
        f32x16 acc[4];
#pragma unroll
        for (int i = 0; i < 4; ++i)
#pragma unroll
            for (int j = 0; j < 16; ++j) acc[i][j] = 0.f;
#pragma unroll
        for (int t4 = 0; t4 < 4; ++t4) {
            bf16x8 a  = *(const bf16x8*)(w1th + (t4 * 64 + lane) * 8);
            bf16x8 al = *(const bf16x8*)(w1tl + (t4 * 64 + lane) * 8);
            acc[t4] = __builtin_amdgcn_mfma_f32_32x32x16_bf16(a,  bvh, acc[t4], 0, 0, 0);
            acc[t4] = __builtin_amdgcn_mfma_f32_32x32x16_bf16(al, bvh, acc[t4], 0, 0, 0);
            acc[t4] = __builtin_amdgcn_mfma_f32_32x32x16_bf16(a,  bvl, acc[t4], 0, 0, 0);
        }
        const float* Pr = P + (size_t)rN * 256;
        const float* Pc = P + (size_t)cN * 256 + 128;
#pragma unroll
        for (int t4 = 0; t4 < 4; ++t4)
#pragma unroll
            for (int g = 0; g < 4; ++g) {
                int nb = t4 * 32 + g * 8 + l5 * 4;
                float4 a1 = *(const float4*)(Pr + nb);
                float4 a2 = *(const float4*)(Pc + nb);
                acc[t4][g * 4 + 0] += a1.x + a2.x;
                acc[t4][g * 4 + 1] += a1.y + a2.y;
                acc[t4][g * 4 + 2] += a1.z + a2.z;
                acc[t4][g * 4 + 3] += a1.w + a2.w;
            }
        // epilogue1: silu + split -> LDS
#pragma unroll
        for (int t4 = 0; t4 < 4; ++t4)
#pragma unroll
            for (int q = 0; q < 4; ++q) {
                int n0 = t4 * 32 + q * 8 + l5 * 4;
                unsigned hp[2], lp[2];
#pragma unroll
                for (int c = 0; c < 2; ++c) {
                    float v0 = silu_f(acc[t4][q * 4 + 2 * c]);
                    float v1 = silu_f(acc[t4][q * 4 + 2 * c + 1]);
                    unsigned u0 = __float_as_uint(v0), u1 = __float_as_uint(v1);
                    hp[c] = (u0 >> 16) | (u1 & 0xFFFF0000u);
                    float r0 = v0 - __uint_as_float(u0 & 0xFFFF0000u);
                    float r1 = v1 - __uint_as_float(u1 & 0xFFFF0000u);
                    lp[c] = (__float_as_uint(r0) >> 16) | (__float_as_uint(r1) & 0xFFFF0000u);
                }
                *(uint2*)(myHi + ll * PAD + n0) = make_uint2(hp[0], hp[1]);
                *(uint2*)(myLo + ll * PAD + n0) = make_uint2(lp[0], lp[1]);
            }
    }

    // ---- GEMM2: t2 = w2^T @ t1, 3-term ----
    f32x16 acc2[4];
#pragma unroll
    for (int i = 0; i < 4; ++i)
#pragma unroll
        for (int j = 0; j < 16; ++j) acc2[i][j] = 0.f;
#pragma unroll
    for (int kc = 0; kc < 8; ++kc) {
        bf16x8 bh = *(const bf16x8*)(myHi + ll * PAD + kc * 16 + l5 * 8);
        bf16x8 bl = *(const bf16x8*)(myLo + ll * PAD + kc * 16 + l5 * 8);
#pragma unroll
        for (int t4 = 0; t4 < 4; ++t4) {
            bf16x8 a  = *(const bf16x8*)(w2a  + ((kc * 4 + t4) * 64 + lane) * 8);
            bf16x8 al = *(const bf16x8*)(w2al + ((kc * 4 + t4) * 64 + lane) * 8);
            acc2[t4] = __builtin_amdgcn_mfma_f32_32x32x16_bf16(a,  bh, acc2[t4], 0, 0, 0);
            acc2[t4] = __builtin_amdgcn_mfma_f32_32x32x16_bf16(al, bh, acc2[t4], 0, 0, 0);
            acc2[t4] = __builtin_amdgcn_mfma_f32_32x32x16_bf16(a,  bl, acc2[t4], 0, 0, 0);
        }
    }
#pragma unroll
    for (int t4 = 0; t4 < 4; ++t4) {
        bf16x8 a  = *(const bf16x8*)(w2a  + ((8 * 4 + t4) * 64 + lane) * 8);
        bf16x8 al = *(const bf16x8*)(w2al + ((8 * 4 + t4) * 64 + lane) * 8);
        acc2[t4] = __builtin_amdgcn_mfma_f32_32x32x16_bf16(a,  bone, acc2[t4], 0, 0, 0);
        acc2[t4] = __builtin_amdgcn_mfma_f32_32x32x16_bf16(al, bone, acc2[t4], 0, 0, 0);
    }

    // ---- attention gate ----
    float att;
    {
        float p = 0.f;
        const float4* aw4 = (const float4*)(awp + (l5 << 6));
#pragma unroll
        for (int t4 = 0; t4 < 4; ++t4)
#pragma unroll
            for (int rq = 0; rq < 4; ++rq) {
                float4 cv = aw4[t4 * 4 + rq];
                p += cv.x * silu_f(acc2[t4][rq * 4 + 0]);
                p += cv.y * silu_f(acc2[t4][rq * 4 + 1]);
                p += cv.z * silu_f(acc2[t4][rq * 4 + 2]);
                p += cv.w * silu_f(acc2[t4][rq * 4 + 3]);
            }
        p += __shfl_xor(p, 32);
        att = sigmoid_f(p + ab[0]);
    }

    // ---- epilogue2: m = silu(t2)*att -> LDS hi+lo (zero for invalid edges) ----
    const bool ev = (e < E);
#pragma unroll
    for (int t4 = 0; t4 < 4; ++t4)
#pragma unroll
        for (int q = 0; q < 4; ++q) {
            int n0 = t4 * 32 + q * 8 + l5 * 4;
            us mh[4], mlo[4];
#pragma unroll
            for (int c = 0; c < 4; ++c) {
                float mv = ev ? silu_f(acc2[t4][q * 4 + c]) * att : 0.f;
                mh[c] = bf16trunc(mv);
                mlo[c] = bf16trunc(mv - bf16tof(mh[c]));
            }
            *(uint2*)(myHi + ll * PAD + n0) = make_uint2(
                (unsigned)mh[0] | ((unsigned)mh[1] << 16),
                (unsigned)mh[2] | ((unsigned)mh[3] << 16));
            *(uint2*)(myLo + ll * PAD + n0) = make_uint2(
                (unsigned)mlo[0] | ((unsigned)mlo[1] << 16),
                (unsigned)mlo[2] | ((unsigned)mlo[3] << 16));
        }

    // ---- GEMM3 (2-term): u = c1^T @ m ----
    f32x16 acc3[4];
#pragma unroll
    for (int i = 0; i < 4; ++i)
#pragma unroll
        for (int j = 0; j < 16; ++j) acc3[i][j] = 0.f;
#pragma unroll
    for (int kc = 0; kc < 8; ++kc) {
        bf16x8 bh = *(const bf16x8*)(myHi + ll * PAD + kc * 16 + l5 * 8);
        bf16x8 bl = *(const bf16x8*)(myLo + ll * PAD + kc * 16 + l5 * 8);
#pragma unroll
        for (int t4 = 0; t4 < 4; ++t4) {
            bf16x8 a = *(const bf16x8*)(c1a + ((kc * 4 + t4) * 64 + lane) * 8);
            acc3[t4] = __builtin_amdgcn_mfma_f32_32x32x16_bf16(a, bh, acc3[t4], 0, 0, 0);
            acc3[t4] = __builtin_amdgcn_mfma_f32_32x32x16_bf16(a, bl, acc3[t4], 0, 0, 0);
        }
    }
#pragma unroll
    for (int t4 = 0; t4 < 4; ++t4) {
        bf16x8 a = *(const bf16x8*)(c1a + ((8 * 4 + t4) * 64 + lane) * 8);
        acc3[t4] = __builtin_amdgcn_mfma_f32_32x32x16_bf16(a, bone, acc3[t4], 0, 0, 0);
    }

    // ---- wc + aggx atomics ----
    {
        float wc = 0.f;
        const float4* cw4 = (const float4*)(cw2p + (l5 << 6));
#pragma unroll
        for (int t4 = 0; t4 < 4; ++t4)
#pragma unroll
            for (int rq = 0; rq < 4; ++rq) {
                float4 cv = cw4[t4 * 4 + rq];
                wc += cv.x * silu_f(acc3[t4][rq * 4 + 0]);
                wc += cv.y * silu_f(acc3[t4][rq * 4 + 1]);
                wc += cv.z * silu_f(acc3[t4][rq * 4 + 2]);
                wc += cv.w * silu_f(acc3[t4][rq * 4 + 3]);
            }
        wc += __shfl_xor(wc, 32);
        if (l5 == 0 && ev) {
            atomicAdd(&aggx[rN * 3 + 0], dx * wc);
            atomicAdd(&aggx[rN * 3 + 1], dy * wc);
            atomicAdd(&aggx[rN * 3 + 2], dz * wc);
        }
    }

    // ---- agg_h: column walk over the wave's 32 sorted edges (m in LDS) ----
    {
        int flag = (ll == 0) ? 1 : (sRW[wv][ll] != sRW[wv][ll - 1]);
        unsigned long long bal = __ballot(flag != 0);
        unsigned m32 = (unsigned)(bal & 0xFFFFFFFFu);
        const int c0 = lane * 2;                     // lane owns cols c0, c0+1
        float s0 = 0.f, s1 = 0.f;
        int node = sRW[wv][0];
        for (int ep = 0; ep < 32; ++ep) {
            unsigned hv = *(const unsigned*)(myHi + ep * PAD + c0);
            unsigned lv = *(const unsigned*)(myLo + ep * PAD + c0);
            s0 += bf16tof((us)(hv & 0xFFFFu)) + bf16tof((us)(lv & 0xFFFFu));
            s1 += bf16tof((us)(hv >> 16)) + bf16tof((us)(lv >> 16));
            bool flush = (ep == 31) || ((m32 >> (ep + 1)) & 1u);
            if (flush) {
                atomicAdd(&aggh[(size_t)node * HID + c0], s0);
                atomicAdd(&aggh[(size_t)node * HID + c0 + 1], s1);
                s0 = 0.f; s1 = 0.f;
                if (ep < 31) node = sRW[wv][ep + 1];
            }
        }
    }
}

// 64 nodes per block (fp32), reads aggh/aggx
__global__ __launch_bounds__(256, 2) void k_node(
    float* __restrict__ h, const float* __restrict__ aggh,
    const float* __restrict__ aggx, const int* __restrict__ cnti,
    float* __restrict__ x, float* __restrict__ vel,
    const float* __restrict__ vw1, const float* __restrict__ vb1,
    const float* __restrict__ vw2, const float* __restrict__ vb2,
    const float* __restrict__ nw1, const float* __restrict__ nb1,
    const float* __restrict__ nw2, const float* __restrict__ nb2,
    int N)
{
    __shared__ __align__(16) float BH[64][132];
    __shared__ __align__(16) float BG[64][132];
    const int t = threadIdx.x;
    const int tx = t & 15, ty = t >> 4;
    const int n0 = blockIdx.x * 64;

    for (int idx = t; idx < 64 * 32; idx += 256) {
        int r = idx >> 5, c4 = idx & 31;
        int n = n0 + r;
        float4 v0 = make_float4(0.f, 0.f, 0.f, 0.f), v1 = v0;
        if (n < N) {
            v0 = *(const float4*)&h[(size_t)n * HID + c4 * 4];
            v1 = *(const float4*)&aggh[(size_t)n * HID + c4 * 4];
        }
        *(float4*)&BH[r][c4 * 4] = v0;
        *(float4*)&BG[r][c4 * 4] = v1;
    }
    __syncthreads();

    {
        float acc[4][8];
#pragma unroll
        for (int i = 0; i < 4; ++i)
#pragma unroll
            for (int j = 0; j < 8; ++j) acc[i][j] = 0.f;
        const float* wp = &vw1[tx * 8];
#pragma unroll 4
        for (int k = 0; k < HID; ++k) {
            float4 w0 = *(const float4*)&wp[k * HID];
            float4 w1v = *(const float4*)&wp[k * HID + 4];
            float wvv[8] = {w0.x, w0.y, w0.z, w0.w, w1v.x, w1v.y, w1v.z, w1v.w};
            float av[4];
#pragma unroll
            for (int i = 0; i < 4; ++i) av[i] = BH[ty * 4 + i][k];
#pragma unroll
            for (int i = 0; i < 4; ++i)
#pragma unroll
                for (int j = 0; j < 8; ++j) acc[i][j] += av[i] * wvv[j];
        }
        float bb[8], w2v[8];
#pragma unroll
        for (int j = 0; j < 8; ++j) { bb[j] = vb1[tx * 8 + j]; w2v[j] = vw2[tx * 8 + j]; }
        float vb20 = vb2[0];
#pragma unroll
        for (int i = 0; i < 4; ++i) {
            float p = 0.f;
#pragma unroll
            for (int j = 0; j < 8; ++j) p += silu_f(acc[i][j] + bb[j]) * w2v[j];
            p += __shfl_xor(p, 1);
            p += __shfl_xor(p, 2);
            p += __shfl_xor(p, 4);
            p += __shfl_xor(p, 8);
            float vs = p + vb20;
            if (tx == 0) {
                int n = n0 + ty * 4 + i;
                if (n < N) {
                    float cc = fmaxf((float)cnti[n], 1.0f);
#pragma unroll
                    for (int d = 0; d < 3; ++d) {
                        float vn = vs * vel[n * 3 + d];
                        float xn = x[n * 3 + d] + aggx[n * 3 + d] / cc + vn;
                        vel[n * 3 + d] = vn;
                        x[n * 3 + d] = xn;
                    }
                }
            }
        }
    }

    float acc2[4][8];
#pragma unroll
    for (int i = 0; i < 4; ++i)
#pragma unroll
        for (int j = 0; j < 8; ++j) acc2[i][j] = 0.f;
    {
        const float* wp = &nw1[tx * 8];
#pragma unroll 4
        for (int k = 0; k < HID; ++k) {
            float4 w0 = *(const float4*)&wp[k * HID];
            float4 w1v = *(const float4*)&wp[k * HID + 4];
            float wvv[8] = {w0.x, w0.y, w0.z, w0.w, w1v.x, w1v.y, w1v.z, w1v.w};
            float av[4];
#pragma unroll
            for (int i = 0; i < 4; ++i) av[i] = BH[ty * 4 + i][k];
#pragma unroll
            for (int i = 0; i < 4; ++i)
#pragma unroll
                for (int j = 0; j < 8; ++j) acc2[i][j] += av[i] * wvv[j];
        }
        const float* wp2 = &nw1[128 * HID + tx * 8];
#pragma unroll 4
        for (int k = 0; k < HID; ++k) {
            float4 w0 = *(const float4*)&wp2[k * HID];
            float4 w1v = *(const float4*)&wp2[k * HID + 4];
            float wvv[8] = {w0.x, w0.y, w0.z, w0.w, w1v.x, w1v.y, w1v.z, w1v.w};
            float av[4];
#pragma unroll
            for (int i = 0; i < 4; ++i) av[i] = BG[ty * 4 + i][k];
#pragma unroll
            for (int i = 0; i < 4; ++i)
#pragma unroll
                for (int j = 0; j < 8; ++j) acc2[i][j] += av[i] * wvv[j];
        }
    }
    __syncthreads();
    {
        float bb[8];
#pragma unroll
        for (int j = 0; j < 8; ++j) bb[j] = nb1[tx * 8 + j];
#pragma unroll
        for (int i = 0; i < 4; ++i)
#pragma unroll
            for (int j = 0; j < 8; ++j)
                BH[ty * 4 + i][tx * 8 + j] = silu_f(acc2[i][j] + bb[j]);
    }
    __syncthreads();
    float acc3[4][8];
#pragma unroll
    for (int i = 0; i < 4; ++i)
#pragma unroll
        for (int j = 0; j < 8; ++j) acc3[i][j] = 0.f;
    {
        const float* wp = &nw2[tx * 8];
#pragma unroll 4
        for (int k = 0; k < HID; ++k) {
            float4 w0 = *(const float4*)&wp[k * HID];
            float4 w1v = *(const float4*)&wp[k * HID + 4];
            float wvv[8] = {w0.x, w0.y, w0.z, w0.w, w1v.x, w1v.y, w1v.z, w1v.w};
            float av[4];
#pragma unroll
            for (int i = 0; i < 4; ++i) av[i] = BH[ty * 4 + i][k];
#pragma unroll
            for (int i = 0; i < 4; ++i)
#pragma unroll
                for (int j = 0; j < 8; ++j) acc3[i][j] += av[i] * wvv[j];
        }
    }
    {
        float bb[8];
#pragma unroll
        for (int j = 0; j < 8; ++j) bb[j] = nb2[tx * 8 + j];
#pragma unroll
        for (int i = 0; i < 4; ++i) {
            int n = n0 + ty * 4 + i;
            if (n < N) {
#pragma unroll
                for (int j = 0; j < 8; ++j)
                    h[(size_t)n * HID + tx * 8 + j] = acc3[i][j] + bb[j];
            }
        }
    }
}

__global__ void k_proj(const float* __restrict__ h, const float* __restrict__ pw,
                       const float* __restrict__ pb, float* __restrict__ out, int N) {
    int idx = blockIdx.x * 256 + threadIdx.x;
    if (idx >= N * 3) return;
    int n = idx / 3, p = idx % 3;
    float s = pb[p];
    const float* hr = &h[(size_t)n * HID];
#pragma unroll 8
    for (int k = 0; k < HID; ++k) s += hr[k] * pw[k * 3 + p];
    out[idx] = s;
}

extern "C" void kernel_launch(void* const* d_in, const int* in_sizes, int n_in,
                              void* d_out, int out_size, void* d_ws, size_t ws_size,
                              hipStream_t stream)
{
    const float* h_in  = (const float*)d_in[0];
    const float* x_in  = (const float*)d_in[1];
    const float* v_in  = (const float*)d_in[2];
    const float* eattr = (const float*)d_in[3];
    const int*   edges = (const int*)d_in[4];
    const float* emb_w = (const float*)d_in[5];
    const float* emb_b = (const float*)d_in[6];
    const float* ew1   = (const float*)d_in[7];
    const float* eb1   = (const float*)d_in[8];
    const float* ew2   = (const float*)d_in[9];
    const float* eb2   = (const float*)d_in[10];
    const float* aw    = (const float*)d_in[11];
    const float* ab    = (const float*)d_in[12];
    const float* nw1   = (const float*)d_in[13];
    const float* nb1   = (const float*)d_in[14];
    const float* nw2   = (const float*)d_in[15];
    const float* nb2   = (const float*)d_in[16];
    const float* cw1   = (const float*)d_in[17];
    const float* cb1   = (const float*)d_in[18];
    const float* cw2   = (const float*)d_in[19];
    const float* vw1   = (const float*)d_in[20];
    const float* vb1   = (const float*)d_in[21];
    const float* vw2   = (const float*)d_in[22];
    const float* vb2   = (const float*)d_in[23];
    const float* pw    = (const float*)d_in[24];
    const float* pb    = (const float*)d_in[25];

    const int N = in_sizes[0] / 6;
    const int E = in_sizes[4] / 2;
    const int* rows = edges;
    const int* cols = edges + E;

    float* ws   = (float*)d_ws;
    float* hbuf = ws;  ws += (size_t)N * HID;
    float* aggh = ws;  ws += (size_t)N * HID;
    float* aggx = ws;  ws += (size_t)N * 3;
    float* xb   = ws;  ws += (size_t)N * 3;
    float* vb   = ws;  ws += (size_t)N * 3;
    float* sea  = ws;  ws += (size_t)E * 2;
    float* Pbuf = ws;  ws += (size_t)N * 256;
    float* awp  = ws;  ws += 4 * 128;
    float* cw2p = ws;  ws += 4 * 128;
    int* wi = (int*)ws;
    int* cnti = wi;  wi += N;
    int* basei = wi; wi += N;
    int* fill = wi;  wi += N;
    int* srow = wi;  wi += E;
    int* scol = wi;  wi += E;
    us* usp = (us*)wi;
    us* w1th = usp;  usp += 4 * 2048;
    us* w1tl = usp;  usp += 4 * 2048;
    us* w2a = usp;   usp += 4 * 18432;
    us* w2al = usp;  usp += 4 * 18432;
    us* c1a = usp;   usp += 4 * 18432;
    float* outp = (float*)d_out;

    hipMemcpyAsync(xb, x_in, (size_t)N * 3 * sizeof(float), hipMemcpyDeviceToDevice, stream);
    hipMemcpyAsync(vb, v_in, (size_t)N * 3 * sizeof(float), hipMemcpyDeviceToDevice, stream);
    hipMemsetAsync(cnti, 0, N * sizeof(int), stream);
    hipMemsetAsync(fill, 0, N * sizeof(int), stream);
    k_cnt<<<(E + 255) / 256, 256, 0, stream>>>(rows, cnti, E);
    k_scan<<<1, 256, 0, stream>>>(cnti, basei, N);
    k_scatter<<<(E + 255) / 256, 256, 0, stream>>>(rows, cols, eattr, basei, fill,
                                                   srow, scol, sea, E);
    {
        const int per = 2048 + 18432 + 18432;
        k_pack_a<<<(4 * per + 1024 + 255) / 256, 256, 0, stream>>>(
            ew1, eb1, ew2, eb2, cw1, cb1, aw, cw2,
            w1th, w1tl, w2a, w2al, c1a, awp, cw2p);
    }
    k_embed<<<(N * HID + 255) / 256, 256, 0, stream>>>(h_in, emb_w, emb_b, hbuf, N);

    for (int l = 0; l < 4; ++l) {
        k_prep_p<<<(N + 63) / 64, 256, 0, stream>>>(hbuf, ew1 + (size_t)l * 33152, Pbuf, N);
        hipMemsetAsync(aggh, 0, (size_t)N * HID * sizeof(float), stream);
        hipMemsetAsync(aggx, 0, (size_t)N * 3 * sizeof(float), stream);
        k_edge_mfma<<<(E + 127) / 128, 256, 0, stream>>>(
            Pbuf, xb, srow, scol, sea,
            w1th + (size_t)l * 2048, w1tl + (size_t)l * 2048,
            w2a + (size_t)l * 18432, w2al + (size_t)l * 18432,
            c1a + (size_t)l * 18432,
            awp + l * 128, cw2p + l * 128, ab + l,
            aggh, aggx, E);
        k_node<<<(N + 63) / 64, 256, 0, stream>>>(
            hbuf, aggh, aggx, cnti, xb, vb,
            vw1 + (size_t)l * HID * HID, vb1 + l * HID, vw2 + l * HID, vb2 + l,
            nw1 + (size_t)l * 2 * HID * HID, nb1 + l * HID,
            nw2 + (size_t)l * HID * HID, nb2 + l * HID, N);
    }
    k_proj<<<(N * 3 + 255) / 256, 256, 0, stream>>>(hbuf, pw, pb, outp, N);
    hipMemcpyAsync(outp + (size_t)N * 3, xb, (size_t)N * 3 * sizeof(float), hipMemcpyDeviceToDevice, stream);
    hipMemcpyAsync(outp + (size_t)N * 6, vb, (size_t)N * 3 * sizeof(float), hipMemcpyDeviceToDevice, stream);
}